// Round 2
// baseline (321.104 us; speedup 1.0000x reference)
//
#include <hip/hip_runtime.h>

#define POOL 7
#define NBIN 49
#define SP_SCALE 0.25f
#define CPT 8   // channels per thread

constexpr int Cc = 256, Hc = 200, Wc = 336;
constexpr int HWc = Hc * Wc;
constexpr int CG = Cc / CPT;  // 32 channel groups

__global__ __launch_bounds__(256) void roi_align_kernel(
    const float* __restrict__ feat, const float* __restrict__ rois,
    float* __restrict__ out, int N) {
  int tid = blockIdx.x * 256 + threadIdx.x;      // covers (n, bin), bin innermost
  if (tid >= N * NBIN) return;
  int bin = tid % NBIN;
  int n   = tid / NBIN;
  int cg  = blockIdx.y;                           // channel group 0..31
  int ph  = bin / POOL, pw = bin % POOL;

  const float* r = rois + (size_t)n * 5;
  int   bidx = (int)r[0];
  float sx = fmaf(r[1], SP_SCALE, -0.5f);
  float sy = fmaf(r[2], SP_SCALE, -0.5f);
  float bw = (fmaf(r[3], SP_SCALE, -0.5f) - sx) * (1.0f / POOL);
  float bh = (fmaf(r[4], SP_SCALE, -0.5f) - sy) * (1.0f / POOL);

  // ---- per-axis sample prep (2 y-samples, 2 x-samples), validity folded into weights
  int yl[2], yh[2]; float wyl[2], wyh[2];
#pragma unroll
  for (int i = 0; i < 2; ++i) {
    float y = sy + ((float)ph + 0.25f + 0.5f * (float)i) * bh;
    bool v = (y > -1.0f) && (y < (float)Hc);
    float y0 = fmaxf(y, 0.0f);
    int lo = (int)y0;  // y0 >= 0 -> trunc == floor
    int hi;
    if (lo >= Hc - 1) { lo = Hc - 1; hi = Hc - 1; y0 = (float)lo; }
    else              { hi = lo + 1; }
    float f = y0 - (float)lo;
    yl[i] = lo; yh[i] = hi;
    wyl[i] = v ? (1.0f - f) : 0.0f;
    wyh[i] = v ? f : 0.0f;
  }
  int xl[2], xh[2]; float wxl[2], wxh[2];
#pragma unroll
  for (int i = 0; i < 2; ++i) {
    float x = sx + ((float)pw + 0.25f + 0.5f * (float)i) * bw;
    bool v = (x > -1.0f) && (x < (float)Wc);
    float x0 = fmaxf(x, 0.0f);
    int lo = (int)x0;
    int hi;
    if (lo >= Wc - 1) { lo = Wc - 1; hi = Wc - 1; x0 = (float)lo; }
    else              { hi = lo + 1; }
    float f = x0 - (float)lo;
    xl[i] = lo; xh[i] = hi;
    wxl[i] = v ? (1.0f - f) : 0.0f;
    wxh[i] = v ? f : 0.0f;
  }

  // ---- 16 (offset, weight) pairs shared by all CPT channels
  int off[16]; float wgt[16];
#pragma unroll
  for (int iy = 0; iy < 2; ++iy) {
#pragma unroll
    for (int ix = 0; ix < 2; ++ix) {
      int k = (iy * 2 + ix) * 4;
      off[k + 0] = yl[iy] * Wc + xl[ix];
      off[k + 1] = yl[iy] * Wc + xh[ix];
      off[k + 2] = yh[iy] * Wc + xl[ix];
      off[k + 3] = yh[iy] * Wc + xh[ix];
      wgt[k + 0] = wyl[iy] * wxl[ix] * 0.25f;
      wgt[k + 1] = wyl[iy] * wxh[ix] * 0.25f;
      wgt[k + 2] = wyh[iy] * wxl[ix] * 0.25f;
      wgt[k + 3] = wyh[iy] * wxh[ix] * 0.25f;
    }
  }

  // ---- gather+accumulate for 8 channels, all loads unconditional
  const float* fp = feat + ((size_t)bidx * Cc + (size_t)cg * CPT) * (size_t)HWc;
  float acc[CPT];
#pragma unroll
  for (int j = 0; j < CPT; ++j) {
    const float* p = fp + (size_t)j * HWc;
    float a = 0.0f;
#pragma unroll
    for (int k = 0; k < 16; ++k) a = fmaf(wgt[k], p[off[k]], a);
    acc[j] = a;
  }

  float* op = out + ((size_t)n * Cc + (size_t)cg * CPT) * NBIN + bin;
#pragma unroll
  for (int j = 0; j < CPT; ++j) op[(size_t)j * NBIN] = acc[j];
}

extern "C" void kernel_launch(void* const* d_in, const int* in_sizes, int n_in,
                              void* d_out, int out_size, void* d_ws, size_t ws_size,
                              hipStream_t stream) {
  const float* feat = (const float*)d_in[0];
  const float* rois = (const float*)d_in[1];
  float* out = (float*)d_out;
  const int N = in_sizes[1] / 5;
  (void)n_in; (void)d_ws; (void)ws_size; (void)out_size;

  dim3 block(256);
  dim3 grid((N * NBIN + 255) / 256, CG);
  roi_align_kernel<<<grid, block, 0, stream>>>(feat, rois, out, N);
}

// Round 3
// 146.813 us; speedup vs baseline: 2.1872x; 2.1872x over previous
//
#include <hip/hip_runtime.h>

#define POOL 7
#define NBIN 49
#define SP_SCALE 0.25f

constexpr int Cc = 256, Hc = 200, Wc = 336;
constexpr int HWc = Hc * Wc;          // 67200 = 32*2100
constexpr int TDIM = 32;

// ---------------- Kernel 1: NCHW -> NHWC transpose into workspace ----------------
__global__ __launch_bounds__(256) void transpose_kernel(
    const float* __restrict__ in, float* __restrict__ outp) {
  __shared__ float tile[TDIM][TDIM + 1];
  int b  = blockIdx.z;
  int p0 = blockIdx.x * TDIM;   // spatial (h*W+w)
  int c0 = blockIdx.y * TDIM;   // channel
  const float* src = in  + (size_t)b * Cc * HWc;
  float*       dst = outp + (size_t)b * Cc * HWc;
  int tx = threadIdx.x;   // 0..31
  int ty = threadIdx.y;   // 0..7
#pragma unroll
  for (int i = 0; i < TDIM; i += 8)
    tile[ty + i][tx] = src[(size_t)(c0 + ty + i) * HWc + (p0 + tx)];
  __syncthreads();
#pragma unroll
  for (int i = 0; i < TDIM; i += 8)
    dst[(size_t)(p0 + ty + i) * Cc + (c0 + tx)] = tile[tx][ty + i];
}

// ---------------- Kernel 2: coalesced gather (lane = channel) ----------------
__global__ __launch_bounds__(256) void gather_kernel(
    const float* __restrict__ ft, const float* __restrict__ rois,
    float* __restrict__ out, int N) {
  int T = N * NBIN;
  // XCD-bijective swizzle: blocks with same blockIdx%8 (same XCD) get contiguous work
  int j = blockIdx.x;
  int q = T >> 3, rr = T & 7;
  int xc = j & 7, loc = j >> 3;
  int w = (xc < rr ? xc * (q + 1) : rr * (q + 1) + (xc - rr) * q) + loc;

  int bin = w % NBIN;
  int n   = w / NBIN;
  int ph  = bin / POOL, pw = bin % POOL;

  const float* r = rois + (size_t)n * 5;
  int   bidx = (int)r[0];
  float sx = fmaf(r[1], SP_SCALE, -0.5f);
  float sy = fmaf(r[2], SP_SCALE, -0.5f);
  float bw = (fmaf(r[3], SP_SCALE, -0.5f) - sx) * (1.0f / POOL);
  float bh = (fmaf(r[4], SP_SCALE, -0.5f) - sy) * (1.0f / POOL);

  int yl[2], yh[2]; float wyl[2], wyh[2];
#pragma unroll
  for (int i = 0; i < 2; ++i) {
    float y = sy + ((float)ph + 0.25f + 0.5f * (float)i) * bh;
    bool v = (y > -1.0f) && (y < (float)Hc);
    float y0 = fmaxf(y, 0.0f);
    int lo = (int)y0;
    int hi;
    if (lo >= Hc - 1) { lo = Hc - 1; hi = Hc - 1; y0 = (float)lo; }
    else              { hi = lo + 1; }
    float f = y0 - (float)lo;
    yl[i] = lo; yh[i] = hi;
    wyl[i] = v ? (1.0f - f) : 0.0f;
    wyh[i] = v ? f : 0.0f;
  }
  int xl[2], xh[2]; float wxl[2], wxh[2];
#pragma unroll
  for (int i = 0; i < 2; ++i) {
    float x = sx + ((float)pw + 0.25f + 0.5f * (float)i) * bw;
    bool v = (x > -1.0f) && (x < (float)Wc);
    float x0 = fmaxf(x, 0.0f);
    int lo = (int)x0;
    int hi;
    if (lo >= Wc - 1) { lo = Wc - 1; hi = Wc - 1; x0 = (float)lo; }
    else              { hi = lo + 1; }
    float f = x0 - (float)lo;
    xl[i] = lo; xh[i] = hi;
    wxl[i] = v ? (1.0f - f) : 0.0f;
    wxh[i] = v ? f : 0.0f;
  }

  int off[16]; float wgt[16];
#pragma unroll
  for (int iy = 0; iy < 2; ++iy) {
#pragma unroll
    for (int ix = 0; ix < 2; ++ix) {
      int k = (iy * 2 + ix) * 4;
      off[k + 0] = yl[iy] * Wc + xl[ix];
      off[k + 1] = yl[iy] * Wc + xh[ix];
      off[k + 2] = yh[iy] * Wc + xl[ix];
      off[k + 3] = yh[iy] * Wc + xh[ix];
      wgt[k + 0] = wyl[iy] * wxl[ix] * 0.25f;
      wgt[k + 1] = wyl[iy] * wxh[ix] * 0.25f;
      wgt[k + 2] = wyh[iy] * wxl[ix] * 0.25f;
      wgt[k + 3] = wyh[iy] * wxh[ix] * 0.25f;
    }
  }

  int t = threadIdx.x;  // channel
  const float* fp = ft + (size_t)bidx * HWc * Cc + t;
  float a = 0.0f;
#pragma unroll
  for (int k = 0; k < 16; ++k)
    a = fmaf(wgt[k], fp[(size_t)off[k] * Cc], a);

  out[((size_t)n * Cc + t) * NBIN + bin] = a;
}

// ---------------- Fallback (round-1 kernel) if workspace too small ----------------
__global__ __launch_bounds__(256) void roi_align_fallback(
    const float* __restrict__ feat, const float* __restrict__ rois,
    float* __restrict__ out, int N) {
  long long idx = (long long)blockIdx.x * blockDim.x + threadIdx.x;
  long long total = (long long)N * Cc * NBIN;
  if (idx >= total) return;
  int pw = (int)(idx % POOL);
  int ph = (int)((idx / POOL) % POOL);
  int c  = (int)((idx / NBIN) % Cc);
  int n  = (int)(idx / ((long long)NBIN * Cc));
  const float* r = rois + (size_t)n * 5;
  int   b  = (int)r[0];
  float sx = fmaf(r[1], SP_SCALE, -0.5f);
  float sy = fmaf(r[2], SP_SCALE, -0.5f);
  float bw = (fmaf(r[3], SP_SCALE, -0.5f) - sx) * (1.0f / POOL);
  float bh = (fmaf(r[4], SP_SCALE, -0.5f) - sy) * (1.0f / POOL);
  const float* fp = feat + ((size_t)b * Cc + c) * (size_t)HWc;
  float acc = 0.0f;
#pragma unroll
  for (int iy = 0; iy < 2; ++iy) {
    float y = sy + ((float)ph + 0.25f + 0.5f * iy) * bh;
    bool vy = (y > -1.0f) && (y < (float)Hc);
    float y0 = fmaxf(y, 0.0f);
    int ylo = (int)y0, yhi;
    if (ylo >= Hc - 1) { ylo = Hc - 1; yhi = Hc - 1; y0 = (float)ylo; }
    else               { yhi = ylo + 1; }
    float ly = y0 - (float)ylo;
#pragma unroll
    for (int ix = 0; ix < 2; ++ix) {
      float x = sx + ((float)pw + 0.25f + 0.5f * ix) * bw;
      bool vx = (x > -1.0f) && (x < (float)Wc);
      float x0 = fmaxf(x, 0.0f);
      int xlo = (int)x0, xhi;
      if (xlo >= Wc - 1) { xlo = Wc - 1; xhi = Wc - 1; x0 = (float)xlo; }
      else               { xhi = xlo + 1; }
      float lx = x0 - (float)xlo;
      if (vy && vx) {
        float v00 = fp[(size_t)ylo * Wc + xlo];
        float v01 = fp[(size_t)ylo * Wc + xhi];
        float v10 = fp[(size_t)yhi * Wc + xlo];
        float v11 = fp[(size_t)yhi * Wc + xhi];
        acc += v00 * (1.0f - ly) * (1.0f - lx) + v01 * (1.0f - ly) * lx
             + v10 * ly * (1.0f - lx) + v11 * ly * lx;
      }
    }
  }
  out[idx] = acc * 0.25f;
}

extern "C" void kernel_launch(void* const* d_in, const int* in_sizes, int n_in,
                              void* d_out, int out_size, void* d_ws, size_t ws_size,
                              hipStream_t stream) {
  const float* feat = (const float*)d_in[0];
  const float* rois = (const float*)d_in[1];
  float* out = (float*)d_out;
  const int N = in_sizes[1] / 5;
  (void)n_in; (void)out_size;

  size_t need = (size_t)2 * Cc * HWc * sizeof(float);  // 137.6 MB NHWC copy
  if (ws_size >= need) {
    float* ft = (float*)d_ws;
    dim3 tb(32, 8);
    dim3 tg(HWc / TDIM, Cc / TDIM, 2);
    transpose_kernel<<<tg, tb, 0, stream>>>(feat, ft);
    int T = N * NBIN;
    gather_kernel<<<T, 256, 0, stream>>>(ft, rois, out, N);
  } else {
    long long total = (long long)N * Cc * NBIN;
    roi_align_fallback<<<(int)((total + 255) / 256), 256, 0, stream>>>(feat, rois, out, N);
  }
}

// Round 4
// 139.895 us; speedup vs baseline: 2.2953x; 1.0495x over previous
//
#include <hip/hip_runtime.h>

#define POOL 7
#define NBIN 49
#define SP_SCALE 0.25f

constexpr int Cc = 256, Hc = 200, Wc = 336;
constexpr int HWc = Hc * Wc;          // 67200

// ---------------- Kernel 1: NCHW -> NHWC transpose (float4 both sides) ----------------
// block (8,32): tx 0..7 covers 32 floats via float4, ty 0..31
__global__ __launch_bounds__(256) void transpose_kernel(
    const float* __restrict__ in, float* __restrict__ outp) {
  __shared__ float tile[32][33];
  int b  = blockIdx.z;
  int p0 = blockIdx.x * 32;   // spatial
  int c0 = blockIdx.y * 32;   // channel
  const float* src = in   + (size_t)b * Cc * HWc;
  float*       dst = outp + (size_t)b * Cc * HWc;
  int tx = threadIdx.x;   // 0..7
  int ty = threadIdx.y;   // 0..31

  float4 v = *(const float4*)(src + (size_t)(c0 + ty) * HWc + p0 + tx * 4);
  tile[ty][tx * 4 + 0] = v.x;
  tile[ty][tx * 4 + 1] = v.y;
  tile[ty][tx * 4 + 2] = v.z;
  tile[ty][tx * 4 + 3] = v.w;
  __syncthreads();
  float4 o;
  o.x = tile[tx * 4 + 0][ty];
  o.y = tile[tx * 4 + 1][ty];
  o.z = tile[tx * 4 + 2][ty];
  o.w = tile[tx * 4 + 3][ty];
  *(float4*)(dst + (size_t)(p0 + ty) * Cc + c0 + tx * 4) = o;
}

// ---------------- Kernel 2: gather, one WAVE per (roi,bin), lane = channel/4 ----------------
__global__ __launch_bounds__(256) void gather_kernel(
    const float* __restrict__ ft, const float* __restrict__ rois,
    float* __restrict__ out, int N) {
  int T  = N * NBIN;
  int nb = (T + 3) >> 2;                // blocks (4 waves = 4 bins each)
  // XCD-bijective swizzle (m204): same-XCD blocks get contiguous bin ranges
  int j = blockIdx.x;
  int q = nb >> 3, rr = nb & 7;
  int xc = j & 7, loc = j >> 3;
  int blk = (xc < rr ? xc * (q + 1) : rr * (q + 1) + (xc - rr) * q) + loc;

  int wv   = threadIdx.x >> 6;          // wave id in block
  int lane = threadIdx.x & 63;
  int w = blk * 4 + wv;
  if (w >= T) return;
  int bin = w % NBIN;
  int n   = w / NBIN;
  int ph  = bin / POOL, pw = bin % POOL;

  const float* r = rois + (size_t)n * 5;
  int   bidx = (int)r[0];
  float sx = fmaf(r[1], SP_SCALE, -0.5f);
  float sy = fmaf(r[2], SP_SCALE, -0.5f);
  float bw = (fmaf(r[3], SP_SCALE, -0.5f) - sx) * (1.0f / POOL);
  float bh = (fmaf(r[4], SP_SCALE, -0.5f) - sy) * (1.0f / POOL);

  int yl[2], yh[2]; float wyl[2], wyh[2];
#pragma unroll
  for (int i = 0; i < 2; ++i) {
    float y = sy + ((float)ph + 0.25f + 0.5f * (float)i) * bh;
    bool v = (y > -1.0f) && (y < (float)Hc);
    float y0 = fmaxf(y, 0.0f);
    int lo = (int)y0;
    int hi;
    if (lo >= Hc - 1) { lo = Hc - 1; hi = Hc - 1; y0 = (float)lo; }
    else              { hi = lo + 1; }
    float f = y0 - (float)lo;
    yl[i] = lo; yh[i] = hi;
    wyl[i] = v ? (1.0f - f) : 0.0f;
    wyh[i] = v ? f : 0.0f;
  }
  int xl[2], xh[2]; float wxl[2], wxh[2];
#pragma unroll
  for (int i = 0; i < 2; ++i) {
    float x = sx + ((float)pw + 0.25f + 0.5f * (float)i) * bw;
    bool v = (x > -1.0f) && (x < (float)Wc);
    float x0 = fmaxf(x, 0.0f);
    int lo = (int)x0;
    int hi;
    if (lo >= Wc - 1) { lo = Wc - 1; hi = Wc - 1; x0 = (float)lo; }
    else              { hi = lo + 1; }
    float f = x0 - (float)lo;
    xl[i] = lo; xh[i] = hi;
    wxl[i] = v ? (1.0f - f) : 0.0f;
    wxh[i] = v ? f : 0.0f;
  }

  int off[16]; float wgt[16];
#pragma unroll
  for (int iy = 0; iy < 2; ++iy) {
#pragma unroll
    for (int ix = 0; ix < 2; ++ix) {
      int k = (iy * 2 + ix) * 4;
      off[k + 0] = yl[iy] * Wc + xl[ix];
      off[k + 1] = yl[iy] * Wc + xh[ix];
      off[k + 2] = yh[iy] * Wc + xl[ix];
      off[k + 3] = yh[iy] * Wc + xh[ix];
      wgt[k + 0] = wyl[iy] * wxl[ix] * 0.25f;
      wgt[k + 1] = wyl[iy] * wxh[ix] * 0.25f;
      wgt[k + 2] = wyh[iy] * wxl[ix] * 0.25f;
      wgt[k + 3] = wyh[iy] * wxh[ix] * 0.25f;
    }
  }

  const float* fp = ft + (size_t)bidx * HWc * Cc + lane * 4;
  float ax = 0.f, ay = 0.f, az = 0.f, aw = 0.f;
#pragma unroll
  for (int k = 0; k < 16; ++k) {
    float4 v = *(const float4*)(fp + (size_t)off[k] * Cc);
    ax = fmaf(wgt[k], v.x, ax);
    ay = fmaf(wgt[k], v.y, ay);
    az = fmaf(wgt[k], v.z, az);
    aw = fmaf(wgt[k], v.w, aw);
  }

  size_t ob = ((size_t)n * Cc + lane * 4) * NBIN + bin;
  out[ob]            = ax;
  out[ob + NBIN]     = ay;
  out[ob + 2 * NBIN] = az;
  out[ob + 3 * NBIN] = aw;
}

// ---------------- Fallback if workspace too small ----------------
__global__ __launch_bounds__(256) void roi_align_fallback(
    const float* __restrict__ feat, const float* __restrict__ rois,
    float* __restrict__ out, int N) {
  long long idx = (long long)blockIdx.x * blockDim.x + threadIdx.x;
  long long total = (long long)N * Cc * NBIN;
  if (idx >= total) return;
  int pw = (int)(idx % POOL);
  int ph = (int)((idx / POOL) % POOL);
  int c  = (int)((idx / NBIN) % Cc);
  int n  = (int)(idx / ((long long)NBIN * Cc));
  const float* r = rois + (size_t)n * 5;
  int   b  = (int)r[0];
  float sx = fmaf(r[1], SP_SCALE, -0.5f);
  float sy = fmaf(r[2], SP_SCALE, -0.5f);
  float bw = (fmaf(r[3], SP_SCALE, -0.5f) - sx) * (1.0f / POOL);
  float bh = (fmaf(r[4], SP_SCALE, -0.5f) - sy) * (1.0f / POOL);
  const float* fp = feat + ((size_t)b * Cc + c) * (size_t)HWc;
  float acc = 0.0f;
#pragma unroll
  for (int iy = 0; iy < 2; ++iy) {
    float y = sy + ((float)ph + 0.25f + 0.5f * iy) * bh;
    bool vy = (y > -1.0f) && (y < (float)Hc);
    float y0 = fmaxf(y, 0.0f);
    int ylo = (int)y0, yhi;
    if (ylo >= Hc - 1) { ylo = Hc - 1; yhi = Hc - 1; y0 = (float)ylo; }
    else               { yhi = ylo + 1; }
    float ly = y0 - (float)ylo;
#pragma unroll
    for (int ix = 0; ix < 2; ++ix) {
      float x = sx + ((float)pw + 0.25f + 0.5f * ix) * bw;
      bool vx = (x > -1.0f) && (x < (float)Wc);
      float x0 = fmaxf(x, 0.0f);
      int xlo = (int)x0, xhi;
      if (xlo >= Wc - 1) { xlo = Wc - 1; xhi = Wc - 1; x0 = (float)xlo; }
      else               { xhi = xlo + 1; }
      float lx = x0 - (float)xlo;
      if (vy && vx) {
        float v00 = fp[(size_t)ylo * Wc + xlo];
        float v01 = fp[(size_t)ylo * Wc + xhi];
        float v10 = fp[(size_t)yhi * Wc + xlo];
        float v11 = fp[(size_t)yhi * Wc + xhi];
        acc += v00 * (1.0f - ly) * (1.0f - lx) + v01 * (1.0f - ly) * lx
             + v10 * ly * (1.0f - lx) + v11 * ly * lx;
      }
    }
  }
  out[idx] = acc * 0.25f;
}

extern "C" void kernel_launch(void* const* d_in, const int* in_sizes, int n_in,
                              void* d_out, int out_size, void* d_ws, size_t ws_size,
                              hipStream_t stream) {
  const float* feat = (const float*)d_in[0];
  const float* rois = (const float*)d_in[1];
  float* out = (float*)d_out;
  const int N = in_sizes[1] / 5;
  (void)n_in; (void)out_size;

  size_t need = (size_t)2 * Cc * HWc * sizeof(float);  // 137.6 MB NHWC copy
  if (ws_size >= need) {
    float* ft = (float*)d_ws;
    dim3 tb(8, 32);
    dim3 tg(HWc / 32, Cc / 32, 2);
    transpose_kernel<<<tg, tb, 0, stream>>>(feat, ft);
    int T = N * NBIN;
    int nb = (T + 3) / 4;
    gather_kernel<<<nb, 256, 0, stream>>>(ft, rois, out, N);
  } else {
    long long total = (long long)N * Cc * NBIN;
    roi_align_fallback<<<(int)((total + 255) / 256), 256, 0, stream>>>(feat, rois, out, N);
  }
}

// Round 5
// 90.060 us; speedup vs baseline: 3.5654x; 1.5533x over previous
//
#include <hip/hip_runtime.h>
#include <hip/hip_fp16.h>

#define POOL 7
#define NBIN 49
#define SP_SCALE 0.25f

constexpr int Cc = 256, Hc = 200, Wc = 336;
constexpr int HWc = Hc * Wc;          // 67200

// ---------------- Kernel 1: NCHW fp32 -> NHWC fp16 transpose ----------------
// block (8,32): tx 0..7 (4 floats each), ty 0..31
__global__ __launch_bounds__(256) void transpose_f16_kernel(
    const float* __restrict__ in, __half* __restrict__ outp) {
  __shared__ float tile[32][33];
  int b  = blockIdx.z;
  int p0 = blockIdx.x * 32;   // spatial
  int c0 = blockIdx.y * 32;   // channel
  const float* src = in   + (size_t)b * Cc * HWc;
  __half*      dst = outp + (size_t)b * Cc * HWc;
  int tx = threadIdx.x;   // 0..7
  int ty = threadIdx.y;   // 0..31

  float4 v = *(const float4*)(src + (size_t)(c0 + ty) * HWc + p0 + tx * 4);
  tile[ty][tx * 4 + 0] = v.x;
  tile[ty][tx * 4 + 1] = v.y;
  tile[ty][tx * 4 + 2] = v.z;
  tile[ty][tx * 4 + 3] = v.w;
  __syncthreads();
  union { __half h[4]; uint2 u; } o;
  o.h[0] = __float2half(tile[tx * 4 + 0][ty]);
  o.h[1] = __float2half(tile[tx * 4 + 1][ty]);
  o.h[2] = __float2half(tile[tx * 4 + 2][ty]);
  o.h[3] = __float2half(tile[tx * 4 + 3][ty]);
  *(uint2*)(dst + (size_t)(p0 + ty) * Cc + c0 + tx * 4) = o.u;
}

// ---------------- Kernel 2: gather. 2 bins/wave, thread = 8 channels (16B loads) ----
__global__ __launch_bounds__(256) void gather_kernel(
    const __half* __restrict__ ft, const float* __restrict__ rois,
    float* __restrict__ out, int N) {
  int T  = N * NBIN;
  int nb = (T + 7) >> 3;                // 8 bins per 256-thread block
  // XCD-bijective swizzle: same-XCD blocks get contiguous ROI ranges
  int j = blockIdx.x;
  int q = nb >> 3, rr = nb & 7;
  int xc = j & 7, loc = j >> 3;
  int blk = (xc < rr ? xc * (q + 1) : rr * (q + 1) + (xc - rr) * q) + loc;

  int sub = threadIdx.x & 31;           // channel chunk: ch = sub*8
  int bl  = threadIdx.x >> 5;           // local bin 0..7
  int w = blk * 8 + bl;
  if (w >= T) return;
  int bin = w % NBIN;
  int n   = w / NBIN;
  int ph  = bin / POOL, pw = bin % POOL;

  const float* r = rois + (size_t)n * 5;
  int   bidx = (int)r[0];
  float sx = fmaf(r[1], SP_SCALE, -0.5f);
  float sy = fmaf(r[2], SP_SCALE, -0.5f);
  float bw = (fmaf(r[3], SP_SCALE, -0.5f) - sx) * (1.0f / POOL);
  float bh = (fmaf(r[4], SP_SCALE, -0.5f) - sy) * (1.0f / POOL);

  int yl[2], yh[2]; float wyl[2], wyh[2];
#pragma unroll
  for (int i = 0; i < 2; ++i) {
    float y = sy + ((float)ph + 0.25f + 0.5f * (float)i) * bh;
    bool v = (y > -1.0f) && (y < (float)Hc);
    float y0 = fmaxf(y, 0.0f);
    int lo = (int)y0;
    int hi;
    if (lo >= Hc - 1) { lo = Hc - 1; hi = Hc - 1; y0 = (float)lo; }
    else              { hi = lo + 1; }
    float f = y0 - (float)lo;
    yl[i] = lo; yh[i] = hi;
    wyl[i] = v ? (1.0f - f) : 0.0f;
    wyh[i] = v ? f : 0.0f;
  }
  int xl[2], xh[2]; float wxl[2], wxh[2];
#pragma unroll
  for (int i = 0; i < 2; ++i) {
    float x = sx + ((float)pw + 0.25f + 0.5f * (float)i) * bw;
    bool v = (x > -1.0f) && (x < (float)Wc);
    float x0 = fmaxf(x, 0.0f);
    int lo = (int)x0;
    int hi;
    if (lo >= Wc - 1) { lo = Wc - 1; hi = Wc - 1; x0 = (float)lo; }
    else              { hi = lo + 1; }
    float f = x0 - (float)lo;
    xl[i] = lo; xh[i] = hi;
    wxl[i] = v ? (1.0f - f) : 0.0f;
    wxh[i] = v ? f : 0.0f;
  }

  int off[16]; float wgt[16];
#pragma unroll
  for (int iy = 0; iy < 2; ++iy) {
#pragma unroll
    for (int ix = 0; ix < 2; ++ix) {
      int k = (iy * 2 + ix) * 4;
      off[k + 0] = yl[iy] * Wc + xl[ix];
      off[k + 1] = yl[iy] * Wc + xh[ix];
      off[k + 2] = yh[iy] * Wc + xl[ix];
      off[k + 3] = yh[iy] * Wc + xh[ix];
      wgt[k + 0] = wyl[iy] * wxl[ix] * 0.25f;
      wgt[k + 1] = wyl[iy] * wxh[ix] * 0.25f;
      wgt[k + 2] = wyh[iy] * wxl[ix] * 0.25f;
      wgt[k + 3] = wyh[iy] * wxh[ix] * 0.25f;
    }
  }

  const __half* fp = ft + (size_t)bidx * HWc * Cc + sub * 8;
  float a0 = 0.f, a1 = 0.f, a2 = 0.f, a3 = 0.f;
  float a4 = 0.f, a5 = 0.f, a6 = 0.f, a7 = 0.f;
#pragma unroll
  for (int k = 0; k < 16; ++k) {
    union { uint4 u; __half2 h2[4]; } v;
    v.u = *(const uint4*)(fp + (size_t)off[k] * Cc);
    float wk = wgt[k];
    float2 f0 = __half22float2(v.h2[0]);
    float2 f1 = __half22float2(v.h2[1]);
    float2 f2 = __half22float2(v.h2[2]);
    float2 f3 = __half22float2(v.h2[3]);
    a0 = fmaf(wk, f0.x, a0); a1 = fmaf(wk, f0.y, a1);
    a2 = fmaf(wk, f1.x, a2); a3 = fmaf(wk, f1.y, a3);
    a4 = fmaf(wk, f2.x, a4); a5 = fmaf(wk, f2.y, a5);
    a6 = fmaf(wk, f3.x, a6); a7 = fmaf(wk, f3.y, a7);
  }

  size_t ob = ((size_t)n * Cc + (size_t)sub * 8) * NBIN + bin;
  out[ob]            = a0;
  out[ob + NBIN]     = a1;
  out[ob + 2 * NBIN] = a2;
  out[ob + 3 * NBIN] = a3;
  out[ob + 4 * NBIN] = a4;
  out[ob + 5 * NBIN] = a5;
  out[ob + 6 * NBIN] = a6;
  out[ob + 7 * NBIN] = a7;
}

// ---------------- Fallback if workspace too small ----------------
__global__ __launch_bounds__(256) void roi_align_fallback(
    const float* __restrict__ feat, const float* __restrict__ rois,
    float* __restrict__ out, int N) {
  long long idx = (long long)blockIdx.x * blockDim.x + threadIdx.x;
  long long total = (long long)N * Cc * NBIN;
  if (idx >= total) return;
  int pw = (int)(idx % POOL);
  int ph = (int)((idx / POOL) % POOL);
  int c  = (int)((idx / NBIN) % Cc);
  int n  = (int)(idx / ((long long)NBIN * Cc));
  const float* r = rois + (size_t)n * 5;
  int   b  = (int)r[0];
  float sx = fmaf(r[1], SP_SCALE, -0.5f);
  float sy = fmaf(r[2], SP_SCALE, -0.5f);
  float bw = (fmaf(r[3], SP_SCALE, -0.5f) - sx) * (1.0f / POOL);
  float bh = (fmaf(r[4], SP_SCALE, -0.5f) - sy) * (1.0f / POOL);
  const float* fp = feat + ((size_t)b * Cc + c) * (size_t)HWc;
  float acc = 0.0f;
#pragma unroll
  for (int iy = 0; iy < 2; ++iy) {
    float y = sy + ((float)ph + 0.25f + 0.5f * iy) * bh;
    bool vy = (y > -1.0f) && (y < (float)Hc);
    float y0 = fmaxf(y, 0.0f);
    int ylo = (int)y0, yhi;
    if (ylo >= Hc - 1) { ylo = Hc - 1; yhi = Hc - 1; y0 = (float)ylo; }
    else               { yhi = ylo + 1; }
    float ly = y0 - (float)ylo;
#pragma unroll
    for (int ix = 0; ix < 2; ++ix) {
      float x = sx + ((float)pw + 0.25f + 0.5f * ix) * bw;
      bool vx = (x > -1.0f) && (x < (float)Wc);
      float x0 = fmaxf(x, 0.0f);
      int xlo = (int)x0, xhi;
      if (xlo >= Wc - 1) { xlo = Wc - 1; xhi = Wc - 1; x0 = (float)xlo; }
      else               { xhi = xlo + 1; }
      float lx = x0 - (float)xlo;
      if (vy && vx) {
        float v00 = fp[(size_t)ylo * Wc + xlo];
        float v01 = fp[(size_t)ylo * Wc + xhi];
        float v10 = fp[(size_t)yhi * Wc + xlo];
        float v11 = fp[(size_t)yhi * Wc + xhi];
        acc += v00 * (1.0f - ly) * (1.0f - lx) + v01 * (1.0f - ly) * lx
             + v10 * ly * (1.0f - lx) + v11 * ly * lx;
      }
    }
  }
  out[idx] = acc * 0.25f;
}

extern "C" void kernel_launch(void* const* d_in, const int* in_sizes, int n_in,
                              void* d_out, int out_size, void* d_ws, size_t ws_size,
                              hipStream_t stream) {
  const float* feat = (const float*)d_in[0];
  const float* rois = (const float*)d_in[1];
  float* out = (float*)d_out;
  const int N = in_sizes[1] / 5;
  (void)n_in; (void)out_size;

  size_t need = (size_t)2 * Cc * HWc * sizeof(__half);  // 68.8 MB NHWC fp16 copy
  if (ws_size >= need) {
    __half* ft = (__half*)d_ws;
    dim3 tb(8, 32);
    dim3 tg(HWc / 32, Cc / 32, 2);
    transpose_f16_kernel<<<tg, tb, 0, stream>>>(feat, ft);
    int T = N * NBIN;
    int nb = (T + 7) / 8;
    gather_kernel<<<nb, 256, 0, stream>>>(ft, rois, out, N);
  } else {
    long long total = (long long)N * Cc * NBIN;
    roi_align_fallback<<<(int)((total + 255) / 256), 256, 0, stream>>>(feat, rois, out, N);
  }
}